// Round 1
// baseline (363.103 us; speedup 1.0000x reference)
//
#include <hip/hip_runtime.h>

#define B_ROWS 4096
#define K_DIM  40960
#define H_DIM  128
#define BM     128
#define BK     64
#define KSPLIT 16
#define KCHUNK (K_DIM / KSPLIT)   // 2560
#define NT     (KCHUNK / BK)      // 40 (even)
#define MT     (B_ROWS / BM)      // 32

typedef __attribute__((ext_vector_type(4))) float f32x4;
typedef __attribute__((ext_vector_type(8))) short short8;

static_assert(KSPLIT * KCHUNK == K_DIM, "ksplit");
static_assert((NT & 1) == 0, "NT even");

// fallback accumulator (atomic path) if ws too small: [2][B_ROWS][H_DIM]
__device__ float g_acc[2u * B_ROWS * H_DIM];

__device__ __forceinline__ unsigned pkbf(float a, float b) {
  // pack 2 f32 -> 2 bf16 (RTN-even), inputs finite
  unsigned ua = __float_as_uint(a), ub = __float_as_uint(b);
  ua = (ua + 0x7fffu + ((ua >> 16) & 1u)) >> 16;
  ub = (ub + 0x7fffu + ((ub >> 16) & 1u)) & 0xffff0000u;
  return ua | ub;
}

template <bool ATOMIC>
__global__ __launch_bounds__(512, 4) void nnue_stage1(
    const float* __restrict__ x1, const float* __restrict__ x2,
    const float* __restrict__ wus, const float* __restrict__ wthem,
    float* __restrict__ part) {
  __shared__ ushort ldsA[2][BM][BK];     // 32 KB
  __shared__ ushort ldsB[2][H_DIM][BK];  // 32 KB

  const int t = threadIdx.x;

  // XCD-aware decode: 32 blocks sharing a (mat,ks) weight chunk -> same XCD
  const int bid  = blockIdx.x;          // 0..1023
  const int xcd  = bid & 7;
  const int slot = bid >> 3;            // 0..127
  const int g    = xcd + 8 * (slot >> 5);  // 0..31 group = (ks,mat)
  const int mt   = slot & 31;
  const int mat  = g & 1;
  const int ks   = g >> 1;

  const float* __restrict__ X = mat ? x2 : x1;
  const float* __restrict__ W = mat ? wthem : wus;

  // ---- staging: tile viewed as [128 rows][16 float4]; thread t owns float4
  // indices t, t+512, t+1024, t+1536 (perfectly coalesced per instruction)
  const int lrow = t >> 4;          // base row, rows r: lrow + 32*r
  const int kf   = (t & 15) * 4;    // f32 offset in BK
  const size_t kbase = (size_t)ks * KCHUNK + kf;
  const float* gA = X + ((size_t)mt * BM + lrow) * K_DIM + kbase;
  const float* gB = W + (size_t)lrow * K_DIM + kbase;

  int wb[4];  // LDS write byte offsets (same for A and B layouts)
  {
    const int slot0 = (t & 15) >> 1;   // 16B slot
    const int rem   = (t & 1) * 8;
    #pragma unroll
    for (int r = 0; r < 4; ++r) {
      const int row = lrow + 32 * r;
      wb[r] = row * (BK * 2) + ((slot0 ^ (row & 7)) * 16) + rem;
    }
  }

  // ---- fragment read offsets (kb=0; kb=1 via ^64)
  const int lane = t & 63;
  const int wid  = t >> 6;
  const int wr   = wid >> 2;  // 0..1  (64 rows each)
  const int wc   = wid & 3;   // 0..3  (32 cols each)
  const int fr   = lane & 15;
  const int lhi  = lane >> 4;

  int offA[4], offB[2];
  #pragma unroll
  for (int i = 0; i < 4; ++i) {
    const int row = wr * 64 + i * 16 + fr;
    offA[i] = row * (BK * 2) + ((lhi ^ (row & 7)) * 16);
  }
  #pragma unroll
  for (int j = 0; j < 2; ++j) {
    const int row = wc * 32 + j * 16 + fr;
    offB[j] = row * (BK * 2) + ((lhi ^ (row & 7)) * 16);
  }

  f32x4 acc[4][2] = {};
  float4 ra0[4], rb0[4], ra1[4], rb1[4];

#define LOADT(s, kt_)                                                       \
  do {                                                                      \
    const float* pa = gA + (size_t)(kt_)*BK;                                \
    const float* pb = gB + (size_t)(kt_)*BK;                                \
    _Pragma("unroll") for (int r = 0; r < 4; ++r) {                         \
      ra##s[r] = *(const float4*)(pa + (size_t)r * 32 * K_DIM);             \
      rb##s[r] = *(const float4*)(pb + (size_t)r * 32 * K_DIM);             \
    }                                                                       \
  } while (0)

#define STAGE(s, buf_)                                                      \
  do {                                                                      \
    char* baseA = (char*)(&ldsA[buf_][0][0]);                               \
    char* baseB = (char*)(&ldsB[buf_][0][0]);                               \
    _Pragma("unroll") for (int r = 0; r < 4; ++r) {                         \
      uint2 pA, pB;                                                         \
      pA.x = pkbf(ra##s[r].x, ra##s[r].y);                                  \
      pA.y = pkbf(ra##s[r].z, ra##s[r].w);                                  \
      pB.x = pkbf(rb##s[r].x, rb##s[r].y);                                  \
      pB.y = pkbf(rb##s[r].z, rb##s[r].w);                                  \
      *(uint2*)(baseA + wb[r]) = pA;                                        \
      *(uint2*)(baseB + wb[r]) = pB;                                        \
    }                                                                       \
  } while (0)

#define MFMA_STEP(buf_)                                                     \
  do {                                                                      \
    const char* baseA = (const char*)(&ldsA[buf_][0][0]);                   \
    const char* baseB = (const char*)(&ldsB[buf_][0][0]);                   \
    _Pragma("unroll") for (int kb = 0; kb < 2; ++kb) {                      \
      short8 af[4], bg[2];                                                  \
      _Pragma("unroll") for (int i = 0; i < 4; ++i)                         \
          af[i] = *(const short8*)(baseA + (offA[i] ^ (kb * 64)));          \
      _Pragma("unroll") for (int j = 0; j < 2; ++j)                         \
          bg[j] = *(const short8*)(baseB + (offB[j] ^ (kb * 64)));          \
      _Pragma("unroll") for (int i = 0; i < 4; ++i)                         \
          _Pragma("unroll") for (int j = 0; j < 2; ++j)                     \
              acc[i][j] = __builtin_amdgcn_mfma_f32_16x16x32_bf16(          \
                  af[i], bg[j], acc[i][j], 0, 0, 0);                        \
    }                                                                       \
  } while (0)

  LOADT(0, 0);
  for (int kt = 0; kt < NT; kt += 2) {
    if (kt + 1 < NT) LOADT(1, kt + 1);   // prefetch in flight across barrier
    STAGE(0, 0);
    __syncthreads();
    MFMA_STEP(0);
    if (kt + 1 < NT) {
      if (kt + 2 < NT) LOADT(0, kt + 2);
      STAGE(1, 1);
      __syncthreads();
      MFMA_STEP(1);
    }
  }

  // ---- epilogue: C/D layout col=lane&15, row=(lane>>4)*4+reg (m89-verified)
  const int browg = mt * BM + wr * 64;
  if (!ATOMIC) {
    float* dst = part + (((size_t)mat * KSPLIT + ks) * B_ROWS) * (size_t)H_DIM;
    #pragma unroll
    for (int i = 0; i < 4; ++i)
      #pragma unroll
      for (int j = 0; j < 2; ++j)
        #pragma unroll
        for (int r = 0; r < 4; ++r) {
          const int rowg = browg + i * 16 + (lhi << 2) + r;
          const int colg = wc * 32 + j * 16 + fr;
          dst[(size_t)rowg * H_DIM + colg] = acc[i][j][r];
        }
  } else {
    float* dst = g_acc + (size_t)mat * B_ROWS * H_DIM;
    #pragma unroll
    for (int i = 0; i < 4; ++i)
      #pragma unroll
      for (int j = 0; j < 2; ++j)
        #pragma unroll
        for (int r = 0; r < 4; ++r) {
          const int rowg = browg + i * 16 + (lhi << 2) + r;
          const int colg = wc * 32 + j * 16 + fr;
          atomicAdd(&dst[(size_t)rowg * H_DIM + colg], acc[i][j][r]);
        }
  }
#undef LOADT
#undef STAGE
#undef MFMA_STEP
}

__global__ void nnue_zero_acc() {
  const unsigned i = blockIdx.x * 256 + threadIdx.x;
  if (i < 2u * B_ROWS * H_DIM) g_acc[i] = 0.f;
}

// one wave per output row; part==nullptr -> read g_acc (KS must be 1)
template <int KS>
__global__ __launch_bounds__(512) void nnue_stage2(
    const float* __restrict__ part, const float* __restrict__ w2,
    float* __restrict__ out) {
  const float* p = part ? part : (const float*)g_acc;
  const int t = threadIdx.x;
  const int l = t & 63, w = t >> 6;
  const int b = blockIdx.x * 8 + w;
  float a0 = 0.f, a1 = 0.f, a2 = 0.f, a3 = 0.f;
  #pragma unroll
  for (int ks = 0; ks < KS; ++ks) {
    const float* p0 = p + ((size_t)ks * B_ROWS + b) * H_DIM;
    const float* p1 = p + (((size_t)KS + ks) * B_ROWS + b) * H_DIM;
    a0 += p0[l];
    a1 += p0[l + 64];
    a2 += p1[l];
    a3 += p1[l + 64];
  }
  float s = fmaxf(a0, 0.f) * w2[l] + fmaxf(a1, 0.f) * w2[l + 64] +
            fmaxf(a2, 0.f) * w2[l + 128] + fmaxf(a3, 0.f) * w2[l + 192];
  #pragma unroll
  for (int off = 32; off; off >>= 1) s += __shfl_xor(s, off, 64);
  if (l == 0) out[b] = s;
}

extern "C" void kernel_launch(void* const* d_in, const int* in_sizes, int n_in,
                              void* d_out, int out_size, void* d_ws,
                              size_t ws_size, hipStream_t stream) {
  const float* x1    = (const float*)d_in[0];
  const float* x2    = (const float*)d_in[1];
  // d_in[2] = turn (unused by reference)
  const float* wus   = (const float*)d_in[3];
  const float* wthem = (const float*)d_in[4];
  const float* w2    = (const float*)d_in[5];
  float* out = (float*)d_out;

  const size_t PART_BYTES =
      2ull * KSPLIT * B_ROWS * H_DIM * sizeof(float);  // 64 MiB

  if (ws_size >= PART_BYTES) {
    float* part = (float*)d_ws;
    nnue_stage1<false><<<MT * KSPLIT * 2, 512, 0, stream>>>(x1, x2, wus, wthem,
                                                            part);
    nnue_stage2<KSPLIT><<<B_ROWS / 8, 512, 0, stream>>>(part, w2, out);
  } else {
    nnue_zero_acc<<<(2 * B_ROWS * H_DIM + 255) / 256, 256, 0, stream>>>();
    nnue_stage1<true><<<MT * KSPLIT * 2, 512, 0, stream>>>(x1, x2, wus, wthem,
                                                           nullptr);
    nnue_stage2<1><<<B_ROWS / 8, 512, 0, stream>>>(nullptr, w2, out);
  }
}

// Round 2
// 300.906 us; speedup vs baseline: 1.2067x; 1.2067x over previous
//
#include <hip/hip_runtime.h>

#define B_ROWS 4096
#define K_DIM  40960
#define H_DIM  128
#define BM     128
#define BK     64
#define KSPLIT 8
#define KCHUNK (K_DIM / KSPLIT)   // 5120
#define NT     (KCHUNK / BK)      // 80 (even)
#define MT     (B_ROWS / BM)      // 32

typedef __attribute__((ext_vector_type(4))) float f32x4;
typedef __attribute__((ext_vector_type(8))) short short8;

static_assert(KSPLIT * KCHUNK == K_DIM, "ksplit");
static_assert((NT & 1) == 0, "NT even");

// fallback accumulator (atomic path) if ws too small: [2][B_ROWS][H_DIM]
__device__ float g_acc[2u * B_ROWS * H_DIM];

__device__ __forceinline__ unsigned pkbf(float a, float b) {
  // pack 2 f32 -> 2 bf16 (RTN-even), inputs finite
  unsigned ua = __float_as_uint(a), ub = __float_as_uint(b);
  ua = (ua + 0x7fffu + ((ua >> 16) & 1u)) >> 16;
  ub = (ub + 0x7fffu + ((ub >> 16) & 1u)) & 0xffff0000u;
  return ua | ub;
}

template <bool ATOMIC>
__global__ __launch_bounds__(512, 4) void nnue_stage1(
    const float* __restrict__ x1, const float* __restrict__ x2,
    const float* __restrict__ wus, const float* __restrict__ wthem,
    float* __restrict__ part) {
  __shared__ ushort ldsA[2][BM][BK];     // 32 KB
  __shared__ ushort ldsB[2][H_DIM][BK];  // 32 KB

  const int t = threadIdx.x;

  // XCD-aware decode: 32 blocks sharing a (mat,ks) weight chunk -> same XCD
  const int bid  = blockIdx.x;             // 0..511
  const int xcd  = bid & 7;
  const int slot = bid >> 3;               // 0..63
  const int g    = xcd + 8 * (slot >> 5);  // 0..15 group = (ks,mat)
  const int mt   = slot & 31;
  const int mat  = g & 1;
  const int ks   = g >> 1;

  const float* __restrict__ X = mat ? x2 : x1;
  const float* __restrict__ W = mat ? wthem : wus;

  // ---- staging: tile viewed as [128 rows][16 float4]; thread t owns float4
  // indices t, t+512, t+1024, t+1536 (coalesced per instruction)
  const int lrow = t >> 4;          // base row, rows r: lrow + 32*r
  const int kf   = (t & 15) * 4;    // f32 offset in BK
  const size_t kbase = (size_t)ks * KCHUNK + kf;
  const float* gA = X + ((size_t)mt * BM + lrow) * K_DIM + kbase;
  const float* gB = W + (size_t)lrow * K_DIM + kbase;

  int wb[4];  // LDS write byte offsets (same layout for A and B)
  {
    const int slot0 = (t & 15) >> 1;  // 16B slot
    const int rem   = (t & 1) * 8;
    #pragma unroll
    for (int r = 0; r < 4; ++r) {
      const int row = lrow + 32 * r;
      wb[r] = row * (BK * 2) + ((slot0 ^ (row & 7)) * 16) + rem;
    }
  }

  // ---- fragment read offsets (kb=0; kb=1 via ^64)
  const int lane = t & 63;
  const int wid  = t >> 6;
  const int wr   = wid >> 2;  // 0..1  (64 rows each)
  const int wc   = wid & 3;   // 0..3  (32 cols each)
  const int fr   = lane & 15;
  const int lhi  = lane >> 4;

  int offA[4], offB[2];
  #pragma unroll
  for (int i = 0; i < 4; ++i) {
    const int row = wr * 64 + i * 16 + fr;
    offA[i] = row * (BK * 2) + ((lhi ^ (row & 7)) * 16);
  }
  #pragma unroll
  for (int j = 0; j < 2; ++j) {
    const int row = wc * 32 + j * 16 + fr;
    offB[j] = row * (BK * 2) + ((lhi ^ (row & 7)) * 16);
  }

  f32x4 acc[4][2] = {};
  f32x4 ra[4], rb[4];  // SINGLE register staging set (LDS is the dbuf)

  // x is streamed once -> nontemporal (don't evict weights from L2/L3).
  // weights are 32-block-shared on the XCD -> normal cached loads.
#define LOADT(kt_)                                                          \
  do {                                                                      \
    const float* pa = gA + (size_t)(kt_)*BK;                                \
    const float* pb = gB + (size_t)(kt_)*BK;                                \
    _Pragma("unroll") for (int r = 0; r < 4; ++r) {                         \
      ra[r] = __builtin_nontemporal_load(                                   \
          (const f32x4*)(pa + (size_t)r * 32 * K_DIM));                     \
      rb[r] = *(const f32x4*)(pb + (size_t)r * 32 * K_DIM);                 \
    }                                                                       \
  } while (0)

#define STAGE(buf_)                                                         \
  do {                                                                      \
    char* baseA = (char*)(&ldsA[buf_][0][0]);                               \
    char* baseB = (char*)(&ldsB[buf_][0][0]);                               \
    _Pragma("unroll") for (int r = 0; r < 4; ++r) {                         \
      uint2 pA, pB;                                                         \
      pA.x = pkbf(ra[r].x, ra[r].y);                                        \
      pA.y = pkbf(ra[r].z, ra[r].w);                                        \
      pB.x = pkbf(rb[r].x, rb[r].y);                                        \
      pB.y = pkbf(rb[r].z, rb[r].w);                                        \
      *(uint2*)(baseA + wb[r]) = pA;                                        \
      *(uint2*)(baseB + wb[r]) = pB;                                        \
    }                                                                       \
  } while (0)

#define MFMA_STEP(buf_)                                                     \
  do {                                                                      \
    const char* baseA = (const char*)(&ldsA[buf_][0][0]);                   \
    const char* baseB = (const char*)(&ldsB[buf_][0][0]);                   \
    _Pragma("unroll") for (int kb = 0; kb < 2; ++kb) {                      \
      short8 af[4], bg[2];                                                  \
      _Pragma("unroll") for (int i = 0; i < 4; ++i)                         \
          af[i] = *(const short8*)(baseA + (offA[i] ^ (kb * 64)));          \
      _Pragma("unroll") for (int j = 0; j < 2; ++j)                         \
          bg[j] = *(const short8*)(baseB + (offB[j] ^ (kb * 64)));          \
      _Pragma("unroll") for (int i = 0; i < 4; ++i)                         \
          _Pragma("unroll") for (int j = 0; j < 2; ++j)                     \
              acc[i][j] = __builtin_amdgcn_mfma_f32_16x16x32_bf16(          \
                  af[i], bg[j], acc[i][j], 0, 0, 0);                        \
    }                                                                       \
  } while (0)

  // prologue: tile 0 -> buf0
  LOADT(0);
  STAGE(0);
  __syncthreads();

  // steady state, 1 barrier per tile:
  //   issue loads(kt+1) -> MFMA(cur) overlaps load flight -> stage(cur^1) -> sync
  for (int kt = 0; kt < NT; kt += 2) {
    LOADT(kt + 1);
    MFMA_STEP(0);
    STAGE(1);
    __syncthreads();
    if (kt + 2 < NT) {
      LOADT(kt + 2);
      MFMA_STEP(1);
      STAGE(0);
      __syncthreads();
    } else {
      MFMA_STEP(1);
    }
  }

  // ---- epilogue: C/D layout col=lane&15, row=(lane>>4)*4+reg (m89-verified)
  const int browg = mt * BM + wr * 64;
  if (!ATOMIC) {
    float* dst = part + (((size_t)mat * KSPLIT + ks) * B_ROWS) * (size_t)H_DIM;
    #pragma unroll
    for (int i = 0; i < 4; ++i)
      #pragma unroll
      for (int j = 0; j < 2; ++j)
        #pragma unroll
        for (int r = 0; r < 4; ++r) {
          const int rowg = browg + i * 16 + (lhi << 2) + r;
          const int colg = wc * 32 + j * 16 + fr;
          __builtin_nontemporal_store(acc[i][j][r],
                                      &dst[(size_t)rowg * H_DIM + colg]);
        }
  } else {
    float* dst = g_acc + (size_t)mat * B_ROWS * H_DIM;
    #pragma unroll
    for (int i = 0; i < 4; ++i)
      #pragma unroll
      for (int j = 0; j < 2; ++j)
        #pragma unroll
        for (int r = 0; r < 4; ++r) {
          const int rowg = browg + i * 16 + (lhi << 2) + r;
          const int colg = wc * 32 + j * 16 + fr;
          atomicAdd(&dst[(size_t)rowg * H_DIM + colg], acc[i][j][r]);
        }
  }
#undef LOADT
#undef STAGE
#undef MFMA_STEP
}

__global__ void nnue_zero_acc() {
  const unsigned i = blockIdx.x * 256 + threadIdx.x;
  if (i < 2u * B_ROWS * H_DIM) g_acc[i] = 0.f;
}

// one wave per output row; part==nullptr -> read g_acc (KS must be 1)
template <int KS>
__global__ __launch_bounds__(512) void nnue_stage2(
    const float* __restrict__ part, const float* __restrict__ w2,
    float* __restrict__ out) {
  const float* p = part ? part : (const float*)g_acc;
  const int t = threadIdx.x;
  const int l = t & 63, w = t >> 6;
  const int b = blockIdx.x * 8 + w;
  float a0 = 0.f, a1 = 0.f, a2 = 0.f, a3 = 0.f;
  #pragma unroll
  for (int ks = 0; ks < KS; ++ks) {
    const float* p0 = p + ((size_t)ks * B_ROWS + b) * H_DIM;
    const float* p1 = p + (((size_t)KS + ks) * B_ROWS + b) * H_DIM;
    a0 += __builtin_nontemporal_load(&p0[l]);
    a1 += __builtin_nontemporal_load(&p0[l + 64]);
    a2 += __builtin_nontemporal_load(&p1[l]);
    a3 += __builtin_nontemporal_load(&p1[l + 64]);
  }
  float s = fmaxf(a0, 0.f) * w2[l] + fmaxf(a1, 0.f) * w2[l + 64] +
            fmaxf(a2, 0.f) * w2[l + 128] + fmaxf(a3, 0.f) * w2[l + 192];
  #pragma unroll
  for (int off = 32; off; off >>= 1) s += __shfl_xor(s, off, 64);
  if (l == 0) out[b] = s;
}

extern "C" void kernel_launch(void* const* d_in, const int* in_sizes, int n_in,
                              void* d_out, int out_size, void* d_ws,
                              size_t ws_size, hipStream_t stream) {
  const float* x1    = (const float*)d_in[0];
  const float* x2    = (const float*)d_in[1];
  // d_in[2] = turn (unused by reference)
  const float* wus   = (const float*)d_in[3];
  const float* wthem = (const float*)d_in[4];
  const float* w2    = (const float*)d_in[5];
  float* out = (float*)d_out;

  const size_t PART_BYTES =
      2ull * KSPLIT * B_ROWS * H_DIM * sizeof(float);  // 32 MiB

  if (ws_size >= PART_BYTES) {
    float* part = (float*)d_ws;
    nnue_stage1<false><<<MT * KSPLIT * 2, 512, 0, stream>>>(x1, x2, wus, wthem,
                                                            part);
    nnue_stage2<KSPLIT><<<B_ROWS / 8, 512, 0, stream>>>(part, w2, out);
  } else {
    nnue_zero_acc<<<(2 * B_ROWS * H_DIM + 255) / 256, 256, 0, stream>>>();
    nnue_stage1<true><<<MT * KSPLIT * 2, 512, 0, stream>>>(x1, x2, wus, wthem,
                                                           nullptr);
    nnue_stage2<1><<<B_ROWS / 8, 512, 0, stream>>>(nullptr, w2, out);
  }
}